// Round 9
// baseline (885.031 us; speedup 1.0000x reference)
//
#include <hip/hip_runtime.h>
#include <math.h>

#define LOOKBACK 336
#define NFEAT    164
#define HORIZON  96
#define DMODEL   64
#define DSTATE   16
#define DINNER   128
#define MLPH     64
#define BATCH    512
#define XCP      132

typedef float v2f __attribute__((ext_vector_type(2)));

__device__ __forceinline__ float fast_rcp(float x) { return __builtin_amdgcn_rcpf(x); }
__device__ __forceinline__ float silu_f(float x) {
    return x * fast_rcp(1.f + __expf(-x));
}

// ============ fused kernel: conv + x_dbl + partial scan; last block of each
// batch performs the cross-segment combine + epilogue + MLP + head ==========
template<int NSEG>
__global__ __launch_bounds__(256, 3) void mamba_fused(
    const float* __restrict__ x_raw,   const float* __restrict__ x_features,
    const float* __restrict__ embed_W, const float* __restrict__ embed_b,
    const float* __restrict__ in_W,
    const float* __restrict__ conv_W,  const float* __restrict__ conv_b,
    const float* __restrict__ xproj_W, const float* __restrict__ dt_W,
    const float* __restrict__ dt_b,    const float* __restrict__ A_log,
    const float* __restrict__ Dvec,    const float* __restrict__ out_W,
    const float* __restrict__ mlp_W1,  const float* __restrict__ mlp_b1,
    const float* __restrict__ mlp_W2,  const float* __restrict__ mlp_b2,
    const float* __restrict__ head_W,  const float* __restrict__ head_b,
    float* __restrict__ ws_h, float* __restrict__ ws_delta,
    float* __restrict__ ws_xclast, int* __restrict__ ws_ctr,
    float* __restrict__ out)
{
    constexpr int SEG = LOOKBACK / NSEG;
    constexpr int NTG = (SEG + 1) / 2;          // A2 t-groups (2 rows each)
    constexpr int BLKS_PER_B = NSEG / 2;
    __shared__ __align__(16) float xrl[2][SEG + 8];
    __shared__ __align__(16) float xprojT[20*XCP];
    __shared__ __align__(16) float xc[2][SEG*XCP];
    __shared__ __align__(16) float Bsh[2][SEG][DSTATE];
    __shared__ __align__(16) float dtraw[2][SEG][4];
    __shared__ __align__(16) float emw_s[DMODEL], emb_s[DMODEL];
    // combine-phase scratch
    __shared__ float xcl[DINNER], zs[DINNER], Cl[DSTATE], yv[DINNER];
    __shared__ float hfin[96], mlph[MLPH];
    __shared__ int amLast;

    const int tid = threadIdx.x;
    const int bid = blockIdx.x;
    const int b  = bid / BLKS_PER_B, sp = bid % BLKS_PER_B;
    const int sh = tid >> 7;                    // segment of the pair (wave-uniform)
    const int ch = tid & 127;
    const int s  = sp*2 + sh;

    // ---- staging ----
    if (ch < SEG + 3) {
        int gt = s*SEG - 3 + ch;
        xrl[sh][ch] = (gt >= 0) ? x_raw[b*LOOKBACK + gt] : 0.f;
    }
    if (tid < DMODEL) { emw_s[tid] = embed_W[tid]; emb_s[tid] = embed_b[tid]; }
    for (int idx = tid; idx < 20*DINNER; idx += 256) {
        int jj = idx >> 7, d = idx & 127;
        xprojT[jj*XCP + d] = xproj_W[d*36 + jj];
    }
    __syncthreads();   // emw_s/emb_s + xrl ready

    // ---- per-thread channel params ----
    float w1 = 0.f, w0 = 0.f;
    for (int dm = 0; dm < DMODEL; ++dm) {       // x-half embed fold (per block)
        float w = in_W[dm*(2*DINNER) + ch];
        w1 = fmaf(emw_s[dm], w, w1);
        w0 = fmaf(emb_s[dm], w, w0);
    }
    const float4 cw = *(const float4*)&conv_W[ch*4];
    const float  cb = conv_b[ch];
    const float dtw0 = dt_W[ch],       dtw1 = dt_W[128 + ch],
                dtw2 = dt_W[256 + ch], dtw3 = dt_W[384 + ch];
    const float dtb_r = dt_b[ch];
    bool structured = true;
    #pragma unroll
    for (int i = 0; i < 16; ++i) {              // own A row structure check
        float a = __expf(A_log[ch*DSTATE + i]);
        float ex = (float)(i + 1);
        structured = structured && (fabsf(a - ex) < 1e-3f * ex);
    }

    // ---- conv+silu ----
    {
        float* xw = &xc[sh][0];
        const float* xr = &xrl[sh][0];
        if (s == 0) {          // zero-padded conv input at sequence start
            for (int tt = 0; tt < SEG; ++tt) {
                float acc = cb;
                if (tt >= 3) acc = fmaf(fmaf(xr[tt],   w1, w0), cw.x, acc);
                if (tt >= 2) acc = fmaf(fmaf(xr[tt+1], w1, w0), cw.y, acc);
                if (tt >= 1) acc = fmaf(fmaf(xr[tt+2], w1, w0), cw.z, acc);
                acc = fmaf(fmaf(xr[tt+3], w1, w0), cw.w, acc);
                xw[tt*XCP + ch] = silu_f(acc);
            }
        } else {               // sliding-window embed reuse
            float e0 = fmaf(xr[0], w1, w0);
            float e1 = fmaf(xr[1], w1, w0);
            float e2 = fmaf(xr[2], w1, w0);
            float v = 0.f;
            for (int tt = 0; tt < SEG; ++tt) {
                float e3 = fmaf(xr[tt+3], w1, w0);
                float acc = cb + e0*cw.x + e1*cw.y + e2*cw.z + e3*cw.w;
                v = silu_f(acc);
                xw[tt*XCP + ch] = v;
                e0 = e1; e1 = e2; e2 = e3;
            }
            if (s == NSEG-1) ws_xclast[b*DINNER + ch] = v;   // t = 335
        }
    }
    __syncthreads();

    // ---- A2: [SEG x 128] @ [128 x 20], 2t x 2j register tiles ----
    for (int task = ch; task < NTG*10; task += 128) {
        const int tg = task / 10;
        const int jp = task - tg*10;
        const int t0 = tg*2;
        const int t1 = (t0+1 < SEG) ? t0+1 : t0;
        const int j0 = jp*2;
        const float* p0 = &xprojT[j0*XCP];
        const float* p1 = &xprojT[(j0+1)*XCP];
        const float* x0 = &xc[sh][t0*XCP];
        const float* x1 = &xc[sh][t1*XCP];
        v2f a00 = {0,0}, a01 = {0,0}, a10 = {0,0}, a11 = {0,0};
        #pragma unroll 8
        for (int d = 0; d < DINNER; d += 4) {
            float4 xv0 = *(const float4*)(x0 + d);
            float4 xv1 = *(const float4*)(x1 + d);
            float4 q0  = *(const float4*)(p0 + d);
            float4 q1  = *(const float4*)(p1 + d);
            v2f x0l = {xv0.x, xv0.y}, x0h = {xv0.z, xv0.w};
            v2f x1l = {xv1.x, xv1.y}, x1h = {xv1.z, xv1.w};
            v2f q0l = {q0.x, q0.y},   q0h = {q0.z, q0.w};
            v2f q1l = {q1.x, q1.y},   q1h = {q1.z, q1.w};
            a00 = __builtin_elementwise_fma(x0l, q0l, a00);
            a00 = __builtin_elementwise_fma(x0h, q0h, a00);
            a01 = __builtin_elementwise_fma(x0l, q1l, a01);
            a01 = __builtin_elementwise_fma(x0h, q1h, a01);
            a10 = __builtin_elementwise_fma(x1l, q0l, a10);
            a10 = __builtin_elementwise_fma(x1h, q0h, a10);
            a11 = __builtin_elementwise_fma(x1l, q1l, a11);
            a11 = __builtin_elementwise_fma(x1h, q1h, a11);
        }
        float r00 = a00.x + a00.y, r01 = a01.x + a01.y;
        float r10 = a10.x + a10.y, r11 = a11.x + a11.y;
        if (j0 < 4) {
            *(float2*)&dtraw[sh][t0][j0] = make_float2(r00, r01);
            if (t1 != t0) *(float2*)&dtraw[sh][t1][j0] = make_float2(r10, r11);
        } else {
            *(float2*)&Bsh[sh][t0][j0-4] = make_float2(r00, r01);
            if (t1 != t0) *(float2*)&Bsh[sh][t1][j0-4] = make_float2(r10, r11);
        }
    }
    __syncthreads();

    // ---- scan: 1 lane per (ch, seg), all 16 states, v2f-packed ----
    const size_t obase = ((size_t)(b*NSEG + s))*(DINNER*DSTATE) + (size_t)ch*DSTATE;
    float dacc = 0.f;
    const float* xs = &xc[sh][0];
    if (__builtin_expect(__all(structured), 1)) {
        v2f h01={0,0},h23={0,0},h45={0,0},h67={0,0},
            h89={0,0},hAB={0,0},hCD={0,0},hEF={0,0};
        #pragma unroll
        for (int tt = 0; tt < SEG; ++tt) {
            float4 dr = *(const float4*)&dtraw[sh][tt][0];       // broadcast
            float dv = fmaf(dr.x, dtw0, fmaf(dr.y, dtw1,
                       fmaf(dr.z, dtw2, fmaf(dr.w, dtw3, dtb_r))));
            float e  = __expf(dv);
            float p  = 1.f + e;
            float r  = fast_rcp(p);                  // exp(-delta)
            float dl = (dv > 80.f) ? dv : __logf(p); // delta
            dacc += dl;
            float ux = dl * xs[tt*XCP + ch];
            float4 B0 = *(const float4*)&Bsh[sh][tt][0];
            float4 B1 = *(const float4*)&Bsh[sh][tt][4];
            float4 B2 = *(const float4*)&Bsh[sh][tt][8];
            float4 B3 = *(const float4*)&Bsh[sh][tt][12];
            float r2 = r*r;
            v2f r2v = {r2, r2};
            v2f p01 = {r, r2};
            v2f p23 = p01*r2v, p45 = p23*r2v, p67 = p45*r2v, p89 = p67*r2v,
                pAB = p89*r2v, pCD = pAB*r2v, pEF = pCD*r2v;
            v2f uxv = {ux, ux};
            h01 = __builtin_elementwise_fma(p01, h01, uxv*(v2f){B0.x,B0.y});
            h23 = __builtin_elementwise_fma(p23, h23, uxv*(v2f){B0.z,B0.w});
            h45 = __builtin_elementwise_fma(p45, h45, uxv*(v2f){B1.x,B1.y});
            h67 = __builtin_elementwise_fma(p67, h67, uxv*(v2f){B1.z,B1.w});
            h89 = __builtin_elementwise_fma(p89, h89, uxv*(v2f){B2.x,B2.y});
            hAB = __builtin_elementwise_fma(pAB, hAB, uxv*(v2f){B2.z,B2.w});
            hCD = __builtin_elementwise_fma(pCD, hCD, uxv*(v2f){B3.x,B3.y});
            hEF = __builtin_elementwise_fma(pEF, hEF, uxv*(v2f){B3.z,B3.w});
        }
        float4* hp = (float4*)&ws_h[obase];
        hp[0] = make_float4(h01.x,h01.y,h23.x,h23.y);
        hp[1] = make_float4(h45.x,h45.y,h67.x,h67.y);
        hp[2] = make_float4(h89.x,h89.y,hAB.x,hAB.y);
        hp[3] = make_float4(hCD.x,hCD.y,hEF.x,hEF.y);
    } else {
        // generic fallback (not taken with reference inputs)
        float hv[16];
        #pragma unroll
        for (int i = 0; i < 16; ++i) hv[i] = 0.f;
        const float* Arow = A_log + ch*DSTATE;
        for (int tt = 0; tt < SEG; ++tt) {
            float4 dr = *(const float4*)&dtraw[sh][tt][0];
            float dv = fmaf(dr.x, dtw0, fmaf(dr.y, dtw1,
                       fmaf(dr.z, dtw2, fmaf(dr.w, dtw3, dtb_r))));
            float e  = __expf(dv);
            float dl = (dv > 15.f) ? dv : __logf(1.f + e);
            dacc += dl;
            float ux = dl * xs[tt*XCP + ch];
            const float* Brow = &Bsh[sh][tt][0];
            for (int i = 0; i < 16; ++i)
                hv[i] = fmaf(__expf(-__expf(Arow[i])*dl), hv[i], ux*Brow[i]);
        }
        float4* hp = (float4*)&ws_h[obase];
        hp[0] = make_float4(hv[0], hv[1], hv[2], hv[3]);
        hp[1] = make_float4(hv[4], hv[5], hv[6], hv[7]);
        hp[2] = make_float4(hv[8], hv[9], hv[10],hv[11]);
        hp[3] = make_float4(hv[12],hv[13],hv[14],hv[15]);
    }
    ws_delta[(b*NSEG + s)*DINNER + ch] = dacc;

    // ==== last-block-done handshake (device-scope; cross-XCD safe) ====
    __syncthreads();                 // all partial writes issued (barrier drains vmcnt)
    if (tid == 0) {
        __threadfence();             // release: make this block's writes visible
        int old = atomicAdd(&ws_ctr[b], 1);
        amLast = (old == BLKS_PER_B - 1);
    }
    __syncthreads();
    if (!amLast) return;
    __threadfence();                 // acquire: see all sibling blocks' writes

    // =================== combine + epilogue for batch b ===================
    const int dB = tid >> 1;
    const int n0 = (tid & 1) * 8;
    bool cstruct = true;
    #pragma unroll
    for (int i = 0; i < 8; ++i) {
        float a = __expf(A_log[dB*DSTATE + n0 + i]);
        float ex = (float)(n0 + i + 1);
        cstruct = cstruct && (fabsf(a - ex) < 1e-3f * ex);
    }

    float dd[NSEG];
    #pragma unroll
    for (int s2 = 1; s2 < NSEG; ++s2)
        dd[s2] = ws_delta[(b*NSEG + s2)*DINNER + dB];
    float hc[8];
    {
        const float4* hp = (const float4*)
            &ws_h[((size_t)b*NSEG + NSEG-1)*(DINNER*DSTATE) + dB*DSTATE + n0];
        float4 a = hp[0], c = hp[1];
        hc[0]=a.x; hc[1]=a.y; hc[2]=a.z; hc[3]=a.w;
        hc[4]=c.x; hc[5]=c.y; hc[6]=c.z; hc[7]=c.w;
    }
    float S = 0.f;
    for (int s2 = NSEG-2; s2 >= 0; --s2) {
        S += dd[s2+1];
        const float4* hp = (const float4*)
            &ws_h[((size_t)b*NSEG + s2)*(DINNER*DSTATE) + dB*DSTATE + n0];
        float4 a = hp[0], c = hp[1];
        float hs[8] = {a.x,a.y,a.z,a.w,c.x,c.y,c.z,c.w};
        if (cstruct) {
            float q = __expf(-S);
            float q2=q*q, q3=q2*q, q4=q2*q2, q5=q4*q, q6=q4*q2, q7=q4*q3, q8=q4*q4;
            float qb = n0 ? q8 : 1.f;
            hc[0]=fmaf(q *qb,hs[0],hc[0]); hc[1]=fmaf(q2*qb,hs[1],hc[1]);
            hc[2]=fmaf(q3*qb,hs[2],hc[2]); hc[3]=fmaf(q4*qb,hs[3],hc[3]);
            hc[4]=fmaf(q5*qb,hs[4],hc[4]); hc[5]=fmaf(q6*qb,hs[5],hc[5]);
            hc[6]=fmaf(q7*qb,hs[6],hc[6]); hc[7]=fmaf(q8*qb,hs[7],hc[7]);
        } else {
            #pragma unroll
            for (int i = 0; i < 8; ++i)
                hc[i] = fmaf(__expf(-__expf(A_log[dB*DSTATE+n0+i])*S), hs[i], hc[i]);
        }
    }

    // ---- ph1: xcl/zs + mlp1 (tid<128); C at t=335 (wave 3) ----
    if (tid < 128) {
        xcl[tid] = ws_xclast[b*DINNER + tid];
        float a1 = 0.f, a0 = 0.f;
        for (int dm = 0; dm < DMODEL; ++dm) {       // z-half embed fold
            float w = in_W[dm*(2*DINNER) + DINNER + tid];
            a1 = fmaf(emw_s[dm], w, a1);
            a0 = fmaf(emb_s[dm], w, a0);
        }
        float zv = fmaf(x_raw[b*LOOKBACK + LOOKBACK-1], a1, a0);
        zs[tid] = silu_f(zv);
        const int j = tid >> 1, k = tid & 1;        // mlp1 lane-pair split
        const float* xf = x_features + b*NFEAT;
        float acc = 0.f;
        const int f0 = k*82, f1 = (k ? NFEAT : 82);
        for (int f = f0; f < f1; ++f)
            acc = fmaf(xf[f], mlp_W1[f*MLPH + j], acc);
        acc += __shfl_xor(acc, 1);
        if (k == 0) mlph[j] = fmaxf(acc + mlp_b1[j], 0.f);
    } else if (tid >= 192) {
        const int lane = tid - 192;
        const int n = lane & 15, q = lane >> 4;     // 4x32 chunks
        const float* xw = ws_xclast + b*DINNER;
        float acc = 0.f;
        for (int d = q*32; d < q*32 + 32; ++d)
            acc = fmaf(xw[d], xproj_W[d*36 + 20 + n], acc);
        acc += __shfl_xor(acc, 16);
        acc += __shfl_xor(acc, 32);
        if (lane < 16) Cl[n] = acc;
    }
    __syncthreads();

    // ---- ph2: mlp2 ----
    if (tid < 64) {
        const int j = tid >> 1, k = tid & 1;
        float acc = 0.f;
        for (int kk = k*32; kk < k*32 + 32; ++kk)
            acc = fmaf(mlph[kk], mlp_W2[kk*32 + j], acc);
        acc += __shfl_xor(acc, 1);
        if (k == 0) hfin[64 + j] = acc + mlp_b2[j];
    }
    __syncthreads();

    // ---- ph3: y = (h·C + xc_last*D) * silu(z) ----
    {
        float part = 0.f;
        #pragma unroll
        for (int i = 0; i < 8; ++i) part = fmaf(hc[i], Cl[n0 + i], part);
        float other = __shfl_xor(part, 1);
        if ((tid & 1) == 0) {
            float y = part + other + xcl[dB]*Dvec[dB];
            yv[dB] = y * zs[dB];
        }
    }
    __syncthreads();

    // ---- ph4: out projection ----
    {
        const int o = tid >> 2, k = tid & 3;
        float acc = 0.f;
        for (int d = k*32; d < k*32 + 32; ++d)
            acc = fmaf(yv[d], out_W[d*DMODEL + o], acc);
        acc += __shfl_xor(acc, 1);
        acc += __shfl_xor(acc, 2);
        if (k == 0) hfin[o] = acc;
    }
    __syncthreads();

    // ---- ph5: head ----
    if (tid < 192) {
        const int o = tid >> 1, k = tid & 1;
        float acc = 0.f;
        for (int i = k*48; i < k*48 + 48; ++i)
            acc = fmaf(hfin[i], head_W[i*HORIZON + o], acc);
        acc += __shfl_xor(acc, 1);
        if (k == 0) out[b*HORIZON + o] = acc + head_b[o];
    }
}

template<int NSEG>
static void launch_impl(void* const* d_in, void* d_out, void* d_ws,
                        hipStream_t stream) {
    float* ws        = (float*)d_ws;
    float* ws_h      = ws;
    float* ws_delta  = ws_h + (size_t)BATCH*NSEG*DINNER*DSTATE;
    float* ws_xclast = ws_delta + (size_t)BATCH*NSEG*DINNER;
    int*   ws_ctr    = (int*)(ws_xclast + (size_t)BATCH*DINNER);

    hipMemsetAsync(ws_ctr, 0, BATCH*sizeof(int), stream);

    mamba_fused<NSEG><<<BATCH*NSEG/2, 256, 0, stream>>>(
        (const float*)d_in[0],  (const float*)d_in[1],  (const float*)d_in[2],
        (const float*)d_in[3],  (const float*)d_in[4],  (const float*)d_in[5],
        (const float*)d_in[6],  (const float*)d_in[7],  (const float*)d_in[8],
        (const float*)d_in[9],  (const float*)d_in[10], (const float*)d_in[11],
        (const float*)d_in[12], (const float*)d_in[13], (const float*)d_in[14],
        (const float*)d_in[15], (const float*)d_in[16], (const float*)d_in[17],
        (const float*)d_in[18],
        ws_h, ws_delta, ws_xclast, ws_ctr,
        (float*)d_out);
}

extern "C" void kernel_launch(void* const* d_in, const int* in_sizes, int n_in,
                              void* d_out, int out_size, void* d_ws, size_t ws_size,
                              hipStream_t stream) {
    (void)in_sizes; (void)n_in; (void)out_size;
    auto need = [](int nseg) {
        return ((size_t)BATCH*nseg*DINNER*DSTATE + (size_t)BATCH*nseg*DINNER
                + (size_t)BATCH*DINNER) * sizeof(float) + BATCH*sizeof(int);
    };
    if (ws_size >= need(16)) launch_impl<16>(d_in, d_out, d_ws, stream);
    else                     launch_impl<8>(d_in, d_out, d_ws, stream);
}

// Round 10
// 211.126 us; speedup vs baseline: 4.1920x; 4.1920x over previous
//
#include <hip/hip_runtime.h>
#include <math.h>

#define LOOKBACK 336
#define NFEAT    164
#define HORIZON  96
#define DMODEL   64
#define DSTATE   16
#define DINNER   128
#define MLPH     64
#define BATCH    512
#define XCP      132

typedef float v2f __attribute__((ext_vector_type(2)));

__device__ __forceinline__ float fast_rcp(float x) { return __builtin_amdgcn_rcpf(x); }
__device__ __forceinline__ float silu_f(float x) {
    return x * fast_rcp(1.f + __expf(-x));
}

// ============ kernel 1: 2 segments/block; conv + x_dbl + partial scan =======
template<int NSEG>
__global__ __launch_bounds__(256, 3) void mamba_part(
    const float* __restrict__ x_raw,
    const float* __restrict__ embed_W, const float* __restrict__ embed_b,
    const float* __restrict__ in_W,
    const float* __restrict__ conv_W,  const float* __restrict__ conv_b,
    const float* __restrict__ xproj_W, const float* __restrict__ dt_W,
    const float* __restrict__ dt_b,    const float* __restrict__ A_log,
    float* __restrict__ ws_h, float* __restrict__ ws_delta,
    float* __restrict__ ws_xclast)
{
    constexpr int SEG = LOOKBACK / NSEG;
    constexpr int TG4 = (SEG + 3) / 4;          // A2 t-groups (4 rows each)
    __shared__ __align__(16) float xrl[2][SEG + 8];
    __shared__ __align__(16) float xprojT[20*XCP];
    __shared__ __align__(16) float xc[2][SEG*XCP];
    __shared__ __align__(16) float Bsh[2][SEG][DSTATE];
    __shared__ __align__(16) float dtraw[2][SEG][4];
    __shared__ __align__(16) float emw_s[DMODEL], emb_s[DMODEL];

    const int tid = threadIdx.x;
    const int bid = blockIdx.x;
    const int b  = bid / (NSEG/2), sp = bid % (NSEG/2);
    const int sh = tid >> 7;                    // segment of the pair (wave-uniform)
    const int ch = tid & 127;
    const int s  = sp*2 + sh;

    // ---- staging ----
    if (ch < SEG + 3) {
        int gt = s*SEG - 3 + ch;
        xrl[sh][ch] = (gt >= 0) ? x_raw[b*LOOKBACK + gt] : 0.f;
    }
    if (tid < DMODEL) { emw_s[tid] = embed_W[tid]; emb_s[tid] = embed_b[tid]; }
    for (int idx = tid; idx < 20*DINNER; idx += 256) {
        int jj = idx >> 7, d = idx & 127;
        xprojT[jj*XCP + d] = xproj_W[d*36 + jj];
    }
    __syncthreads();   // emw_s/emb_s + xrl ready

    // ---- per-thread channel params ----
    float w1 = 0.f, w0 = 0.f;
    for (int dm = 0; dm < DMODEL; ++dm) {       // x-half embed fold (coalesced)
        float w = in_W[dm*(2*DINNER) + ch];
        w1 = fmaf(emw_s[dm], w, w1);
        w0 = fmaf(emb_s[dm], w, w0);
    }
    const float4 cw = *(const float4*)&conv_W[ch*4];
    const float  cb = conv_b[ch];
    const float dtw0 = dt_W[ch],       dtw1 = dt_W[128 + ch],
                dtw2 = dt_W[256 + ch], dtw3 = dt_W[384 + ch];
    const float dtb_r = dt_b[ch];
    bool structured = true;
    #pragma unroll
    for (int i = 0; i < 16; ++i) {
        float a = __expf(A_log[ch*DSTATE + i]);
        float ex = (float)(i + 1);
        structured = structured && (fabsf(a - ex) < 1e-3f * ex);
    }

    // ---- conv+silu ----
    {
        float* xw = &xc[sh][0];
        const float* xr = &xrl[sh][0];
        if (s == 0) {          // zero-padded conv input at sequence start
            for (int tt = 0; tt < SEG; ++tt) {
                float acc = cb;
                if (tt >= 3) acc = fmaf(fmaf(xr[tt],   w1, w0), cw.x, acc);
                if (tt >= 2) acc = fmaf(fmaf(xr[tt+1], w1, w0), cw.y, acc);
                if (tt >= 1) acc = fmaf(fmaf(xr[tt+2], w1, w0), cw.z, acc);
                acc = fmaf(fmaf(xr[tt+3], w1, w0), cw.w, acc);
                xw[tt*XCP + ch] = silu_f(acc);
            }
        } else {               // sliding-window embed reuse
            float e0 = fmaf(xr[0], w1, w0);
            float e1 = fmaf(xr[1], w1, w0);
            float e2 = fmaf(xr[2], w1, w0);
            float v = 0.f;
            for (int tt = 0; tt < SEG; ++tt) {
                float e3 = fmaf(xr[tt+3], w1, w0);
                float acc = cb + e0*cw.x + e1*cw.y + e2*cw.z + e3*cw.w;
                v = silu_f(acc);
                xw[tt*XCP + ch] = v;
                e0 = e1; e1 = e2; e2 = e3;
            }
            if (s == NSEG-1) ws_xclast[b*DINNER + ch] = v;   // t = 335
        }
    }
    __syncthreads();

    // ---- A2: [SEG x 128] @ [128 x 20], 4t x 2j register tiles ----
    // 4 xc rows amortize each xproj read: 6 b128 per 16 pk-fma (was 4 per 8)
    for (int task = ch; task < TG4*10; task += 128) {
        const int tg = task / 10;
        const int jp = task - tg*10;
        const int t0 = tg*4;
        const int j0 = jp*2;
        const float* p0 = &xprojT[j0*XCP];
        const float* p1 = &xprojT[(j0+1)*XCP];
        const float* xb = &xc[sh][0];
        int ti[4];
        #pragma unroll
        for (int r = 0; r < 4; ++r) ti[r] = (t0+r < SEG) ? t0+r : SEG-1;
        v2f a0[4], a1[4];
        #pragma unroll
        for (int r = 0; r < 4; ++r) { a0[r] = (v2f){0,0}; a1[r] = (v2f){0,0}; }
        #pragma unroll 4
        for (int d = 0; d < DINNER; d += 4) {
            float4 q0 = *(const float4*)(p0 + d);
            float4 q1 = *(const float4*)(p1 + d);
            v2f q0l = {q0.x, q0.y}, q0h = {q0.z, q0.w};
            v2f q1l = {q1.x, q1.y}, q1h = {q1.z, q1.w};
            #pragma unroll
            for (int r = 0; r < 4; ++r) {
                float4 xv = *(const float4*)(xb + ti[r]*XCP + d);
                v2f xl = {xv.x, xv.y}, xh = {xv.z, xv.w};
                a0[r] = __builtin_elementwise_fma(xl, q0l, a0[r]);
                a0[r] = __builtin_elementwise_fma(xh, q0h, a0[r]);
                a1[r] = __builtin_elementwise_fma(xl, q1l, a1[r]);
                a1[r] = __builtin_elementwise_fma(xh, q1h, a1[r]);
            }
        }
        #pragma unroll
        for (int r = 0; r < 4; ++r) {
            if (t0 + r < SEG) {
                float v0 = a0[r].x + a0[r].y, v1 = a1[r].x + a1[r].y;
                if (j0 < 4) *(float2*)&dtraw[sh][t0+r][j0] = make_float2(v0, v1);
                else        *(float2*)&Bsh[sh][t0+r][j0-4] = make_float2(v0, v1);
            }
        }
    }
    __syncthreads();

    // ---- scan: 1 lane per (ch, seg), all 16 states, v2f-packed ----
    const size_t obase = ((size_t)(b*NSEG + s))*(DINNER*DSTATE) + (size_t)ch*DSTATE;
    float dacc = 0.f;
    const float* xs = &xc[sh][0];
    if (__builtin_expect(__all(structured), 1)) {
        v2f h01={0,0},h23={0,0},h45={0,0},h67={0,0},
            h89={0,0},hAB={0,0},hCD={0,0},hEF={0,0};
        #pragma unroll
        for (int tt = 0; tt < SEG; ++tt) {
            float4 dr = *(const float4*)&dtraw[sh][tt][0];       // broadcast
            float dv = fmaf(dr.x, dtw0, fmaf(dr.y, dtw1,
                       fmaf(dr.z, dtw2, fmaf(dr.w, dtw3, dtb_r))));
            float e  = __expf(dv);
            float p  = 1.f + e;
            float r  = fast_rcp(p);                  // exp(-delta)
            float dl = (dv > 80.f) ? dv : __logf(p); // delta
            dacc += dl;
            float ux = dl * xs[tt*XCP + ch];
            float4 B0 = *(const float4*)&Bsh[sh][tt][0];
            float4 B1 = *(const float4*)&Bsh[sh][tt][4];
            float4 B2 = *(const float4*)&Bsh[sh][tt][8];
            float4 B3 = *(const float4*)&Bsh[sh][tt][12];
            float r2 = r*r;
            v2f r2v = {r2, r2};
            v2f p01 = {r, r2};
            v2f p23 = p01*r2v, p45 = p23*r2v, p67 = p45*r2v, p89 = p67*r2v,
                pAB = p89*r2v, pCD = pAB*r2v, pEF = pCD*r2v;
            v2f uxv = {ux, ux};
            h01 = __builtin_elementwise_fma(p01, h01, uxv*(v2f){B0.x,B0.y});
            h23 = __builtin_elementwise_fma(p23, h23, uxv*(v2f){B0.z,B0.w});
            h45 = __builtin_elementwise_fma(p45, h45, uxv*(v2f){B1.x,B1.y});
            h67 = __builtin_elementwise_fma(p67, h67, uxv*(v2f){B1.z,B1.w});
            h89 = __builtin_elementwise_fma(p89, h89, uxv*(v2f){B2.x,B2.y});
            hAB = __builtin_elementwise_fma(pAB, hAB, uxv*(v2f){B2.z,B2.w});
            hCD = __builtin_elementwise_fma(pCD, hCD, uxv*(v2f){B3.x,B3.y});
            hEF = __builtin_elementwise_fma(pEF, hEF, uxv*(v2f){B3.z,B3.w});
        }
        float4* hp = (float4*)&ws_h[obase];
        hp[0] = make_float4(h01.x,h01.y,h23.x,h23.y);
        hp[1] = make_float4(h45.x,h45.y,h67.x,h67.y);
        hp[2] = make_float4(h89.x,h89.y,hAB.x,hAB.y);
        hp[3] = make_float4(hCD.x,hCD.y,hEF.x,hEF.y);
    } else {
        // generic fallback (not taken with reference inputs)
        float hv[16];
        #pragma unroll
        for (int i = 0; i < 16; ++i) hv[i] = 0.f;
        const float* Arow = A_log + ch*DSTATE;
        for (int tt = 0; tt < SEG; ++tt) {
            float4 dr = *(const float4*)&dtraw[sh][tt][0];
            float dv = fmaf(dr.x, dtw0, fmaf(dr.y, dtw1,
                       fmaf(dr.z, dtw2, fmaf(dr.w, dtw3, dtb_r))));
            float e  = __expf(dv);
            float dl = (dv > 15.f) ? dv : __logf(1.f + e);
            dacc += dl;
            float ux = dl * xs[tt*XCP + ch];
            const float* Brow = &Bsh[sh][tt][0];
            for (int i = 0; i < 16; ++i)
                hv[i] = fmaf(__expf(-__expf(Arow[i])*dl), hv[i], ux*Brow[i]);
        }
        float4* hp = (float4*)&ws_h[obase];
        hp[0] = make_float4(hv[0], hv[1], hv[2], hv[3]);
        hp[1] = make_float4(hv[4], hv[5], hv[6], hv[7]);
        hp[2] = make_float4(hv[8], hv[9], hv[10],hv[11]);
        hp[3] = make_float4(hv[12],hv[13],hv[14],hv[15]);
    }
    ws_delta[(b*NSEG + s)*DINNER + ch] = dacc;
}

// ============ kernel 2: combine segments + epilogue + MLP + head ============
template<int NSEG>
__global__ __launch_bounds__(256, 2) void mamba_combine(
    const float* __restrict__ x_raw, const float* __restrict__ x_features,
    const float* __restrict__ embed_W, const float* __restrict__ embed_b,
    const float* __restrict__ in_W,
    const float* __restrict__ xproj_W, const float* __restrict__ A_log,
    const float* __restrict__ Dvec, const float* __restrict__ out_W,
    const float* __restrict__ mlp_W1, const float* __restrict__ mlp_b1,
    const float* __restrict__ mlp_W2, const float* __restrict__ mlp_b2,
    const float* __restrict__ head_W, const float* __restrict__ head_b,
    const float* __restrict__ ws_h, const float* __restrict__ ws_delta,
    const float* __restrict__ ws_xclast,
    float* __restrict__ out)
{
    __shared__ float xcl[DINNER], zs[DINNER], Cl[DSTATE], yv[DINNER];
    __shared__ float hfin[96], mlph[MLPH];

    const int tid = threadIdx.x;
    const int b   = blockIdx.x;
    const int dB  = tid >> 1;
    const int n0  = (tid & 1) * 8;

    bool cstruct = true;
    #pragma unroll
    for (int i = 0; i < 8; ++i) {
        float a = __expf(A_log[dB*DSTATE + n0 + i]);
        float ex = (float)(n0 + i + 1);
        cstruct = cstruct && (fabsf(a - ex) < 1e-3f * ex);
    }

    // ---- combine partial h over segments (suffix delta sums) ----
    float dd[NSEG];
    #pragma unroll
    for (int s2 = 1; s2 < NSEG; ++s2)
        dd[s2] = ws_delta[(b*NSEG + s2)*DINNER + dB];
    float hc[8];
    {
        const float4* hp = (const float4*)
            &ws_h[((size_t)b*NSEG + NSEG-1)*(DINNER*DSTATE) + dB*DSTATE + n0];
        float4 a = hp[0], c = hp[1];
        hc[0]=a.x; hc[1]=a.y; hc[2]=a.z; hc[3]=a.w;
        hc[4]=c.x; hc[5]=c.y; hc[6]=c.z; hc[7]=c.w;
    }
    float S = 0.f;
    for (int s2 = NSEG-2; s2 >= 0; --s2) {
        S += dd[s2+1];
        const float4* hp = (const float4*)
            &ws_h[((size_t)b*NSEG + s2)*(DINNER*DSTATE) + dB*DSTATE + n0];
        float4 a = hp[0], c = hp[1];
        float hs[8] = {a.x,a.y,a.z,a.w,c.x,c.y,c.z,c.w};
        if (cstruct) {
            float q = __expf(-S);
            float q2=q*q, q3=q2*q, q4=q2*q2, q5=q4*q, q6=q4*q2, q7=q4*q3, q8=q4*q4;
            float qb = n0 ? q8 : 1.f;
            hc[0]=fmaf(q *qb,hs[0],hc[0]); hc[1]=fmaf(q2*qb,hs[1],hc[1]);
            hc[2]=fmaf(q3*qb,hs[2],hc[2]); hc[3]=fmaf(q4*qb,hs[3],hc[3]);
            hc[4]=fmaf(q5*qb,hs[4],hc[4]); hc[5]=fmaf(q6*qb,hs[5],hc[5]);
            hc[6]=fmaf(q7*qb,hs[6],hc[6]); hc[7]=fmaf(q8*qb,hs[7],hc[7]);
        } else {
            #pragma unroll
            for (int i = 0; i < 8; ++i)
                hc[i] = fmaf(__expf(-__expf(A_log[dB*DSTATE+n0+i])*S), hs[i], hc[i]);
        }
    }

    // ---- ph1: xcl/zs (z-half embed fold inline) + mlp1; C at t=335 ----
    if (tid < 128) {
        xcl[tid] = ws_xclast[b*DINNER + tid];
        float a1 = 0.f, a0 = 0.f;
        for (int dm = 0; dm < DMODEL; ++dm) {
            float w = in_W[dm*(2*DINNER) + DINNER + tid];
            a1 = fmaf(embed_W[dm], w, a1);    // embed_* uniform -> scalar loads
            a0 = fmaf(embed_b[dm], w, a0);
        }
        float zv = fmaf(x_raw[b*LOOKBACK + LOOKBACK-1], a1, a0);
        zs[tid] = silu_f(zv);
        const int j = tid >> 1, k = tid & 1;        // mlp1 lane-pair split
        const float* xf = x_features + b*NFEAT;
        float acc = 0.f;
        const int f0 = k*82, f1 = (k ? NFEAT : 82);
        for (int f = f0; f < f1; ++f)
            acc = fmaf(xf[f], mlp_W1[f*MLPH + j], acc);
        acc += __shfl_xor(acc, 1);
        if (k == 0) mlph[j] = fmaxf(acc + mlp_b1[j], 0.f);
    } else if (tid >= 192) {
        const int lane = tid - 192;
        const int n = lane & 15, q = lane >> 4;     // 4x32 chunks
        const float* xw = ws_xclast + b*DINNER;
        float acc = 0.f;
        for (int d = q*32; d < q*32 + 32; ++d)
            acc = fmaf(xw[d], xproj_W[d*36 + 20 + n], acc);
        acc += __shfl_xor(acc, 16);
        acc += __shfl_xor(acc, 32);
        if (lane < 16) Cl[n] = acc;
    }
    __syncthreads();

    // ---- ph2: mlp2 ----
    if (tid < 64) {
        const int j = tid >> 1, k = tid & 1;
        float acc = 0.f;
        for (int kk = k*32; kk < k*32 + 32; ++kk)
            acc = fmaf(mlph[kk], mlp_W2[kk*32 + j], acc);
        acc += __shfl_xor(acc, 1);
        if (k == 0) hfin[64 + j] = acc + mlp_b2[j];
    }
    __syncthreads();

    // ---- ph3: y = (h·C + xc_last*D) * silu(z) ----
    {
        float part = 0.f;
        #pragma unroll
        for (int i = 0; i < 8; ++i) part = fmaf(hc[i], Cl[n0 + i], part);
        float other = __shfl_xor(part, 1);
        if ((tid & 1) == 0) {
            float y = part + other + xcl[dB]*Dvec[dB];
            yv[dB] = y * zs[dB];
        }
    }
    __syncthreads();

    // ---- ph4: out projection ----
    {
        const int o = tid >> 2, k = tid & 3;
        float acc = 0.f;
        for (int d = k*32; d < k*32 + 32; ++d)
            acc = fmaf(yv[d], out_W[d*DMODEL + o], acc);
        acc += __shfl_xor(acc, 1);
        acc += __shfl_xor(acc, 2);
        if (k == 0) hfin[o] = acc;
    }
    __syncthreads();

    // ---- ph5: head ----
    if (tid < 192) {
        const int o = tid >> 1, k = tid & 1;
        float acc = 0.f;
        for (int i = k*48; i < k*48 + 48; ++i)
            acc = fmaf(hfin[i], head_W[i*HORIZON + o], acc);
        acc += __shfl_xor(acc, 1);
        if (k == 0) out[b*HORIZON + o] = acc + head_b[o];
    }
}

template<int NSEG>
static void launch_impl(void* const* d_in, void* d_out, void* d_ws,
                        hipStream_t stream) {
    float* ws        = (float*)d_ws;
    float* ws_h      = ws;
    float* ws_delta  = ws_h + (size_t)BATCH*NSEG*DINNER*DSTATE;
    float* ws_xclast = ws_delta + (size_t)BATCH*NSEG*DINNER;

    mamba_part<NSEG><<<BATCH*NSEG/2, 256, 0, stream>>>(
        (const float*)d_in[0], (const float*)d_in[2], (const float*)d_in[3],
        (const float*)d_in[4], (const float*)d_in[5], (const float*)d_in[6],
        (const float*)d_in[7], (const float*)d_in[8], (const float*)d_in[9],
        (const float*)d_in[10],
        ws_h, ws_delta, ws_xclast);

    mamba_combine<NSEG><<<BATCH, 256, 0, stream>>>(
        (const float*)d_in[0],  (const float*)d_in[1],  (const float*)d_in[2],
        (const float*)d_in[3],  (const float*)d_in[4],  (const float*)d_in[7],
        (const float*)d_in[10], (const float*)d_in[11], (const float*)d_in[12],
        (const float*)d_in[13], (const float*)d_in[14], (const float*)d_in[15],
        (const float*)d_in[16], (const float*)d_in[17], (const float*)d_in[18],
        ws_h, ws_delta, ws_xclast,
        (float*)d_out);
}

extern "C" void kernel_launch(void* const* d_in, const int* in_sizes, int n_in,
                              void* d_out, int out_size, void* d_ws, size_t ws_size,
                              hipStream_t stream) {
    (void)in_sizes; (void)n_in; (void)out_size;
    auto need = [](int nseg) {
        return ((size_t)BATCH*nseg*DINNER*DSTATE + (size_t)BATCH*nseg*DINNER
                + (size_t)BATCH*DINNER) * sizeof(float);
    };
    if (ws_size >= need(16)) launch_impl<16>(d_in, d_out, d_ws, stream);
    else                     launch_impl<8>(d_in, d_out, d_ws, stream);
}

// Round 11
// 203.484 us; speedup vs baseline: 4.3494x; 1.0376x over previous
//
#include <hip/hip_runtime.h>
#include <math.h>

#define LOOKBACK 336
#define NFEAT    164
#define HORIZON  96
#define DMODEL   64
#define DSTATE   16
#define DINNER   128
#define MLPH     64
#define BATCH    512
#define XCP      132
#define NG       4      // channel-groups (time segments) per block
#define GSEG     84     // timesteps per group (4*84 = 336)
#define CHK      21     // timesteps per chunk
#define NCH      4      // chunks per group

typedef float v2f __attribute__((ext_vector_type(2)));

__device__ __forceinline__ float fast_rcp(float x) { return __builtin_amdgcn_rcpf(x); }
__device__ __forceinline__ float silu_f(float x) {
    return x * fast_rcp(1.f + __expf(-x));
}

// One dispatch does everything: 4 time-segments scanned in parallel by 4
// 128-lane groups, then an in-block segment-combine + epilogue + MLP + head.
__global__ __launch_bounds__(512, 2) void mamba_one(
    const float* __restrict__ x_raw,   const float* __restrict__ x_features,
    const float* __restrict__ embed_W, const float* __restrict__ embed_b,
    const float* __restrict__ in_W,
    const float* __restrict__ conv_W,  const float* __restrict__ conv_b,
    const float* __restrict__ xproj_W, const float* __restrict__ dt_W,
    const float* __restrict__ dt_b,    const float* __restrict__ A_log,
    const float* __restrict__ Dvec,    const float* __restrict__ out_W,
    const float* __restrict__ mlp_W1,  const float* __restrict__ mlp_b1,
    const float* __restrict__ mlp_W2,  const float* __restrict__ mlp_b2,
    const float* __restrict__ head_W,  const float* __restrict__ head_b,
    float* __restrict__ out)
{
    __shared__ __align__(16) float xrl[344];            // xrl[i] = x_raw[i-3], zero-pad i<3
    __shared__ __align__(16) float xprojT[20*XCP];
    __shared__ __align__(16) float xc[NG][CHK*XCP];     // per-group conv out (chunk)
    __shared__ __align__(16) float Bsh[NG][CHK][DSTATE];
    __shared__ __align__(16) float dtraw[NG][CHK][4];
    __shared__ __align__(16) float emw_s[DMODEL], emb_s[DMODEL];
    __shared__ float xcl[DINNER], zsil[DINNER], Cl[DSTATE], yv[DINNER];
    __shared__ float hfin[96], mlph[MLPH];

    const int tid = threadIdx.x;
    const int b   = blockIdx.x;
    const int g   = tid >> 7;            // group 0..3 (2 waves each, wave-uniform)
    const int ch  = tid & 127;

    // ---- staging ----
    for (int i = tid; i < 339; i += 512) {
        int gt = i - 3;
        xrl[i] = (gt >= 0) ? x_raw[b*LOOKBACK + gt] : 0.f;
    }
    if (tid < DMODEL) { emw_s[tid] = embed_W[tid]; emb_s[tid] = embed_b[tid]; }
    for (int idx = tid; idx < 20*DINNER; idx += 512) {
        int jj = idx >> 7, d = idx & 127;
        xprojT[jj*XCP + d] = xproj_W[d*36 + jj];
    }
    __syncthreads();

    // ---- per-thread channel params ----
    float w1 = 0.f, w0 = 0.f;
    for (int dm = 0; dm < DMODEL; ++dm) {       // x-half embed fold (coalesced)
        float w = in_W[dm*(2*DINNER) + ch];
        w1 = fmaf(emw_s[dm], w, w1);
        w0 = fmaf(emb_s[dm], w, w0);
    }
    const float4 cw = *(const float4*)&conv_W[ch*4];
    const float  cb = conv_b[ch];
    const float dtw0 = dt_W[ch],       dtw1 = dt_W[128 + ch],
                dtw2 = dt_W[256 + ch], dtw3 = dt_W[384 + ch];
    const float dtb_r = dt_b[ch];
    bool structured = true;
    #pragma unroll
    for (int i = 0; i < 16; ++i) {
        float a = __expf(A_log[ch*DSTATE + i]);
        float ex = (float)(i + 1);
        structured = structured && (fabsf(a - ex) < 1e-3f * ex);
    }
    const bool sfast = __all(structured);

    // ---- main loop: per chunk {conv | A2 | scan}, phase-locked groups ----
    v2f h01={0,0},h23={0,0},h45={0,0},h67={0,0},
        h89={0,0},hAB={0,0},hCD={0,0},hEF={0,0};
    float dacc = 0.f;                            // sum of delta over this group

    for (int c = 0; c < NCH; ++c) {
        const int t0g = g*GSEG + c*CHK;          // global t of chunk start

        // conv+silu into xc[g]
        {
            float* xw = &xc[g][0];
            const float* xr = &xrl[t0g];         // xr[k] = x_raw[t0g-3+k]
            if (g == 0 && c == 0) {              // zero-pad: skip taps t<0
                for (int tt = 0; tt < CHK; ++tt) {
                    float acc = cb;
                    if (tt >= 3) acc = fmaf(fmaf(xr[tt],   w1, w0), cw.x, acc);
                    if (tt >= 2) acc = fmaf(fmaf(xr[tt+1], w1, w0), cw.y, acc);
                    if (tt >= 1) acc = fmaf(fmaf(xr[tt+2], w1, w0), cw.z, acc);
                    acc = fmaf(fmaf(xr[tt+3], w1, w0), cw.w, acc);
                    xw[tt*XCP + ch] = silu_f(acc);
                }
            } else {                             // sliding-window embed reuse
                float e0 = fmaf(xr[0], w1, w0);
                float e1 = fmaf(xr[1], w1, w0);
                float e2 = fmaf(xr[2], w1, w0);
                float v = 0.f;
                for (int tt = 0; tt < CHK; ++tt) {
                    float e3 = fmaf(xr[tt+3], w1, w0);
                    float acc = cb + e0*cw.x + e1*cw.y + e2*cw.z + e3*cw.w;
                    v = silu_f(acc);
                    xw[tt*XCP + ch] = v;
                    e0 = e1; e1 = e2; e2 = e3;
                }
                if (g == NG-1 && c == NCH-1) xcl[ch] = v;   // t = 335
            }
        }
        __syncthreads();

        // A2: [21 x 128] @ [128 x 20] -> dtraw(4)+Bsh(16); 110 tasks, 2t x 2j
        if (ch < 110) {
            const int tg = ch / 10;
            const int j0 = (ch - tg*10) * 2;
            const int t0 = tg*2;
            const int t1 = (t0+1 < CHK) ? t0+1 : t0;
            const float* p0 = &xprojT[j0*XCP];
            const float* p1 = &xprojT[(j0+1)*XCP];
            const float* x0 = &xc[g][t0*XCP];
            const float* x1 = &xc[g][t1*XCP];
            v2f a00 = {0,0}, a01 = {0,0}, a10 = {0,0}, a11 = {0,0};
            #pragma unroll 8
            for (int d = 0; d < DINNER; d += 4) {
                float4 xv0 = *(const float4*)(x0 + d);
                float4 xv1 = *(const float4*)(x1 + d);
                float4 q0  = *(const float4*)(p0 + d);
                float4 q1  = *(const float4*)(p1 + d);
                v2f x0l = {xv0.x, xv0.y}, x0h = {xv0.z, xv0.w};
                v2f x1l = {xv1.x, xv1.y}, x1h = {xv1.z, xv1.w};
                v2f q0l = {q0.x, q0.y},   q0h = {q0.z, q0.w};
                v2f q1l = {q1.x, q1.y},   q1h = {q1.z, q1.w};
                a00 = __builtin_elementwise_fma(x0l, q0l, a00);
                a00 = __builtin_elementwise_fma(x0h, q0h, a00);
                a01 = __builtin_elementwise_fma(x0l, q1l, a01);
                a01 = __builtin_elementwise_fma(x0h, q1h, a01);
                a10 = __builtin_elementwise_fma(x1l, q0l, a10);
                a10 = __builtin_elementwise_fma(x1h, q0h, a10);
                a11 = __builtin_elementwise_fma(x1l, q1l, a11);
                a11 = __builtin_elementwise_fma(x1h, q1h, a11);
            }
            float r00 = a00.x + a00.y, r01 = a01.x + a01.y;
            float r10 = a10.x + a10.y, r11 = a11.x + a11.y;
            if (j0 < 4) {
                *(float2*)&dtraw[g][t0][j0] = make_float2(r00, r01);
                if (t1 != t0) *(float2*)&dtraw[g][t1][j0] = make_float2(r10, r11);
            } else {
                *(float2*)&Bsh[g][t0][j0-4] = make_float2(r00, r01);
                if (t1 != t0) *(float2*)&Bsh[g][t1][j0-4] = make_float2(r10, r11);
            }
        }
        __syncthreads();

        // scan chunk: 1 lane per (ch, group), all 16 states, v2f-packed
        const float* xs = &xc[g][0];
        if (__builtin_expect(sfast, 1)) {
            #pragma unroll
            for (int tt = 0; tt < CHK; ++tt) {
                float4 dr = *(const float4*)&dtraw[g][tt][0];    // broadcast
                float dv = fmaf(dr.x, dtw0, fmaf(dr.y, dtw1,
                           fmaf(dr.z, dtw2, fmaf(dr.w, dtw3, dtb_r))));
                float e  = __expf(dv);
                float p  = 1.f + e;
                float r  = fast_rcp(p);                  // exp(-delta)
                float dl = (dv > 80.f) ? dv : __logf(p); // delta
                dacc += dl;
                float ux = dl * xs[tt*XCP + ch];
                float4 B0 = *(const float4*)&Bsh[g][tt][0];
                float4 B1 = *(const float4*)&Bsh[g][tt][4];
                float4 B2 = *(const float4*)&Bsh[g][tt][8];
                float4 B3 = *(const float4*)&Bsh[g][tt][12];
                float r2 = r*r;
                v2f r2v = {r2, r2};
                v2f p01 = {r, r2};
                v2f p23 = p01*r2v, p45 = p23*r2v, p67 = p45*r2v, p89 = p67*r2v,
                    pAB = p89*r2v, pCD = pAB*r2v, pEF = pCD*r2v;
                v2f uxv = {ux, ux};
                h01 = __builtin_elementwise_fma(p01, h01, uxv*(v2f){B0.x,B0.y});
                h23 = __builtin_elementwise_fma(p23, h23, uxv*(v2f){B0.z,B0.w});
                h45 = __builtin_elementwise_fma(p45, h45, uxv*(v2f){B1.x,B1.y});
                h67 = __builtin_elementwise_fma(p67, h67, uxv*(v2f){B1.z,B1.w});
                h89 = __builtin_elementwise_fma(p89, h89, uxv*(v2f){B2.x,B2.y});
                hAB = __builtin_elementwise_fma(pAB, hAB, uxv*(v2f){B2.z,B2.w});
                hCD = __builtin_elementwise_fma(pCD, hCD, uxv*(v2f){B3.x,B3.y});
                hEF = __builtin_elementwise_fma(pEF, hEF, uxv*(v2f){B3.z,B3.w});
            }
        } else {
            // generic fallback (not taken with reference inputs)
            const float* Arow = A_log + ch*DSTATE;
            for (int tt = 0; tt < CHK; ++tt) {
                float4 dr = *(const float4*)&dtraw[g][tt][0];
                float dv = fmaf(dr.x, dtw0, fmaf(dr.y, dtw1,
                           fmaf(dr.z, dtw2, fmaf(dr.w, dtw3, dtb_r))));
                float e  = __expf(dv);
                float dl = (dv > 15.f) ? dv : __logf(1.f + e);
                dacc += dl;
                float ux = dl * xs[tt*XCP + ch];
                const float* Brow = &Bsh[g][tt][0];
                float hv[16] = {h01.x,h01.y,h23.x,h23.y,h45.x,h45.y,h67.x,h67.y,
                                h89.x,h89.y,hAB.x,hAB.y,hCD.x,hCD.y,hEF.x,hEF.y};
                for (int i = 0; i < 16; ++i)
                    hv[i] = fmaf(__expf(-__expf(Arow[i])*dl), hv[i], ux*Brow[i]);
                h01=(v2f){hv[0],hv[1]};   h23=(v2f){hv[2],hv[3]};
                h45=(v2f){hv[4],hv[5]};   h67=(v2f){hv[6],hv[7]};
                h89=(v2f){hv[8],hv[9]};   hAB=(v2f){hv[10],hv[11]};
                hCD=(v2f){hv[12],hv[13]}; hEF=(v2f){hv[14],hv[15]};
            }
        }
        __syncthreads();   // xc/dtraw/Bsh reads done before next chunk's writes
    }

    // ---- write partials to LDS (overlay dead xc / Bsh regions) ----
    float* hpart = &xc[0][0];            // needs 8192 floats, xc has 11088
    float* dsum  = &Bsh[0][0][0];        // needs 512 floats, Bsh has 1344
    {
        float4* hp = (float4*)&hpart[(g*128 + ch)*16];
        hp[0] = make_float4(h01.x,h01.y,h23.x,h23.y);
        hp[1] = make_float4(h45.x,h45.y,h67.x,h67.y);
        hp[2] = make_float4(h89.x,h89.y,hAB.x,hAB.y);
        hp[3] = make_float4(hCD.x,hCD.y,hEF.x,hEF.y);
        dsum[g*128 + ch] = dacc;
    }
    __syncthreads();

    // ---- E1 (parallel): combine | z-gate | C | mlp1 ----
    float H[16];
    if (tid < 128) {
        // sequential chain over groups: H = exp(A*D_g)*H + h_g
        {
            const float4* hp = (const float4*)&hpart[tid*16];
            float4 a = hp[0], bq = hp[1], cq = hp[2], dq = hp[3];
            H[0]=a.x;  H[1]=a.y;  H[2]=a.z;  H[3]=a.w;
            H[4]=bq.x; H[5]=bq.y; H[6]=bq.z; H[7]=bq.w;
            H[8]=cq.x; H[9]=cq.y; H[10]=cq.z;H[11]=cq.w;
            H[12]=dq.x;H[13]=dq.y;H[14]=dq.z;H[15]=dq.w;
        }
        for (int gg = 1; gg < NG; ++gg) {
            float D = dsum[gg*128 + tid];
            const float4* hp = (const float4*)&hpart[(gg*128 + tid)*16];
            float4 a = hp[0], bq = hp[1], cq = hp[2], dq = hp[3];
            float hg[16] = {a.x,a.y,a.z,a.w,bq.x,bq.y,bq.z,bq.w,
                            cq.x,cq.y,cq.z,cq.w,dq.x,dq.y,dq.z,dq.w};
            if (structured) {
                float r = __expf(-D);
                float pw = 1.f;
                #pragma unroll
                for (int i = 0; i < 16; ++i) {
                    pw *= r;                      // r^(i+1)
                    H[i] = fmaf(pw, H[i], hg[i]);
                }
            } else {
                #pragma unroll
                for (int i = 0; i < 16; ++i)
                    H[i] = fmaf(__expf(-__expf(A_log[tid*DSTATE+i])*D), H[i], hg[i]);
            }
        }
    } else if (tid < 256) {
        const int c2 = tid - 128;                 // z-gate channel
        float a1 = 0.f, a0 = 0.f;
        for (int dm = 0; dm < DMODEL; ++dm) {
            float w = in_W[dm*(2*DINNER) + DINNER + c2];
            a1 = fmaf(emw_s[dm], w, a1);
            a0 = fmaf(emb_s[dm], w, a0);
        }
        float zv = fmaf(xrl[338], a1, a0);        // x_raw[335]
        zsil[c2] = silu_f(zv);
    } else if (tid < 320) {
        const int lane = tid - 256;               // C at t=335 (one wave)
        const int n = lane & 15, q = lane >> 4;   // 4 chunks of 32 d
        float acc = 0.f;
        for (int d = q*32; d < q*32 + 32; ++d)
            acc = fmaf(xcl[d], xproj_W[d*36 + 20 + n], acc);
        acc += __shfl_xor(acc, 16);
        acc += __shfl_xor(acc, 32);
        if (lane < 16) Cl[n] = acc;
    } else if (tid >= 384) {
        const int lane = tid - 384;               // mlp1 (2 waves)
        const int j = lane >> 1, k = lane & 1;
        const float* xf = x_features + b*NFEAT;
        float acc = 0.f;
        const int f0 = k*82, f1 = (k ? NFEAT : 82);
        for (int f = f0; f < f1; ++f)
            acc = fmaf(xf[f], mlp_W1[f*MLPH + j], acc);
        acc += __shfl_xor(acc, 1);
        if (k == 0) mlph[j] = fmaxf(acc + mlp_b1[j], 0.f);
    }
    __syncthreads();

    // ---- E2: y (tid<128) | mlp2 (tid 128..191) ----
    if (tid < 128) {
        float acc = 0.f;
        #pragma unroll
        for (int i = 0; i < 16; ++i) acc = fmaf(H[i], Cl[i], acc);
        float y = acc + xcl[tid]*Dvec[tid];
        yv[tid] = y * zsil[tid];
    } else if (tid < 192) {
        const int lane = tid - 128;
        const int j = lane >> 1, k = lane & 1;
        float acc = 0.f;
        for (int kk = k*32; kk < k*32 + 32; ++kk)
            acc = fmaf(mlph[kk], mlp_W2[kk*32 + j], acc);
        acc += __shfl_xor(acc, 1);
        if (k == 0) hfin[64 + j] = acc + mlp_b2[j];
    }
    __syncthreads();

    // ---- E3: out projection (tid<256) ----
    if (tid < 256) {
        const int o = tid >> 2, k = tid & 3;
        float acc = 0.f;
        for (int d = k*32; d < k*32 + 32; ++d)
            acc = fmaf(yv[d], out_W[d*DMODEL + o], acc);
        acc += __shfl_xor(acc, 1);
        acc += __shfl_xor(acc, 2);
        if (k == 0) hfin[o] = acc;
    }
    __syncthreads();

    // ---- E4: head ----
    if (tid < 192) {
        const int o = tid >> 1, k = tid & 1;
        float acc = 0.f;
        for (int i = k*48; i < k*48 + 48; ++i)
            acc = fmaf(hfin[i], head_W[i*HORIZON + o], acc);
        acc += __shfl_xor(acc, 1);
        if (k == 0) out[b*HORIZON + o] = acc + head_b[o];
    }
}

extern "C" void kernel_launch(void* const* d_in, const int* in_sizes, int n_in,
                              void* d_out, int out_size, void* d_ws, size_t ws_size,
                              hipStream_t stream) {
    (void)in_sizes; (void)n_in; (void)out_size; (void)d_ws; (void)ws_size;
    mamba_one<<<BATCH, 512, 0, stream>>>(
        (const float*)d_in[0],  (const float*)d_in[1],  (const float*)d_in[2],
        (const float*)d_in[3],  (const float*)d_in[4],  (const float*)d_in[5],
        (const float*)d_in[6],  (const float*)d_in[7],  (const float*)d_in[8],
        (const float*)d_in[9],  (const float*)d_in[10], (const float*)d_in[11],
        (const float*)d_in[12], (const float*)d_in[13], (const float*)d_in[14],
        (const float*)d_in[15], (const float*)d_in[16], (const float*)d_in[17],
        (const float*)d_in[18], (float*)d_out);
}

// Round 12
// 173.619 us; speedup vs baseline: 5.0975x; 1.1720x over previous
//
#include <hip/hip_runtime.h>
#include <math.h>

#define LOOKBACK 336
#define NFEAT    164
#define HORIZON  96
#define DMODEL   64
#define DSTATE   16
#define DINNER   128
#define MLPH     64
#define BATCH    512
#define XCP      132
#define NG       4      // channel-groups (time segments) per block
#define GSEG     84     // timesteps per group
#define CHK      12     // timesteps per chunk
#define NCH      7      // chunks per group (7*12 = 84)
#define HSTR     20     // hpart record stride (breaks stride-16 bank aliasing)

typedef float v2f __attribute__((ext_vector_type(2)));

__device__ __forceinline__ float fast_rcp(float x) { return __builtin_amdgcn_rcpf(x); }
__device__ __forceinline__ float silu_f(float x) {
    return x * fast_rcp(1.f + __expf(-x));
}

// Single dispatch: 4 time-segments scanned by 4 128-lane groups with
// double-buffered xc so conv(c+1) overlaps scan(c) in one phase (R4 trick),
// then in-block segment-combine + epilogue + MLP + head.
__global__ __launch_bounds__(512, 2) void mamba_one(
    const float* __restrict__ x_raw,   const float* __restrict__ x_features,
    const float* __restrict__ embed_W, const float* __restrict__ embed_b,
    const float* __restrict__ in_W,
    const float* __restrict__ conv_W,  const float* __restrict__ conv_b,
    const float* __restrict__ xproj_W, const float* __restrict__ dt_W,
    const float* __restrict__ dt_b,    const float* __restrict__ A_log,
    const float* __restrict__ Dvec,    const float* __restrict__ out_W,
    const float* __restrict__ mlp_W1,  const float* __restrict__ mlp_b1,
    const float* __restrict__ mlp_W2,  const float* __restrict__ mlp_b2,
    const float* __restrict__ head_W,  const float* __restrict__ head_b,
    float* __restrict__ out)
{
    __shared__ __align__(16) float xrl[344];            // xrl[i]=x_raw[i-3], pad i<3
    __shared__ __align__(16) float xprojT[20*XCP];      // 10.6 KB
    __shared__ __align__(16) float xcbuf[2][NG][CHK*XCP]; // 50.7 KB double-buffered
    __shared__ __align__(16) float Bsh[NG][CHK][DSTATE];
    __shared__ __align__(16) float dtraw[NG][CHK][4];
    __shared__ float xcl[DINNER], zsil[DINNER], Cl[DSTATE], yv[DINNER];
    __shared__ float hfin[96], mlph[MLPH];

    const int tid = threadIdx.x;
    const int b   = blockIdx.x;
    const int g   = tid >> 7;            // group 0..3 (2 waves, wave-uniform)
    const int ch  = tid & 127;

    // ---- staging ----
    for (int i = tid; i < 339; i += 512)
        xrl[i] = (i >= 3) ? x_raw[b*LOOKBACK + i - 3] : 0.f;
    for (int idx = tid; idx < 20*DINNER; idx += 512) {
        int jj = idx >> 7, d = idx & 127;
        xprojT[jj*XCP + d] = xproj_W[d*36 + jj];
    }

    // ---- per-thread channel params (embed_* uniform -> scalar loads) ----
    float w1 = 0.f, w0 = 0.f;
    for (int dm = 0; dm < DMODEL; ++dm) {
        float w = in_W[dm*(2*DINNER) + ch];
        w1 = fmaf(embed_W[dm], w, w1);
        w0 = fmaf(embed_b[dm], w, w0);
    }
    const float4 cw = *(const float4*)&conv_W[ch*4];
    const float  cb = conv_b[ch];
    const float dtw0 = dt_W[ch],       dtw1 = dt_W[128 + ch],
                dtw2 = dt_W[256 + ch], dtw3 = dt_W[384 + ch];
    const float dtb_r = dt_b[ch];
    bool structured = true;
    #pragma unroll
    for (int i = 0; i < 16; ++i) {
        float a = __expf(A_log[ch*DSTATE + i]);
        float ex = (float)(i + 1);
        structured = structured && (fabsf(a - ex) < 1e-3f * ex);
    }
    const bool sfast = __all(structured);
    __syncthreads();   // xrl/xprojT ready

    // ---- conv chunk 0 into buffer 0 ----
    {
        float* xw = &xcbuf[0][g][0];
        const float* xr = &xrl[g*GSEG];
        if (g == 0) {        // zero-padded taps at sequence start
            for (int tt = 0; tt < CHK; ++tt) {
                float acc = cb;
                if (tt >= 3) acc = fmaf(fmaf(xr[tt],   w1, w0), cw.x, acc);
                if (tt >= 2) acc = fmaf(fmaf(xr[tt+1], w1, w0), cw.y, acc);
                if (tt >= 1) acc = fmaf(fmaf(xr[tt+2], w1, w0), cw.z, acc);
                acc = fmaf(fmaf(xr[tt+3], w1, w0), cw.w, acc);
                xw[tt*XCP + ch] = silu_f(acc);
            }
        } else {
            float e0 = fmaf(xr[0], w1, w0);
            float e1 = fmaf(xr[1], w1, w0);
            float e2 = fmaf(xr[2], w1, w0);
            #pragma unroll
            for (int tt = 0; tt < CHK; ++tt) {
                float e3 = fmaf(xr[tt+3], w1, w0);
                float acc = cb + e0*cw.x + e1*cw.y + e2*cw.z + e3*cw.w;
                xw[tt*XCP + ch] = silu_f(acc);
                e0 = e1; e1 = e2; e2 = e3;
            }
        }
    }
    __syncthreads();

    // ---- main loop: A2(c) | bar | scan(c) || conv(c+1) | bar ----
    v2f h01={0,0},h23={0,0},h45={0,0},h67={0,0},
        h89={0,0},hAB={0,0},hCD={0,0},hEF={0,0};
    float dacc = 0.f;

    for (int c = 0; c < NCH; ++c) {
        const int buf = c & 1;

        // A2: [12 x 128] @ [128 x 20] -> dtraw(4)+Bsh(16); 120 tasks, 1t x 2j
        if (ch < 120) {
            const int tt = ch / 10;
            const int j0 = (ch - tt*10) * 2;
            const float* p0   = &xprojT[j0*XCP];
            const float* p1   = &xprojT[(j0+1)*XCP];
            const float* xrow = &xcbuf[buf][g][tt*XCP];
            v2f a0 = {0,0}, a1 = {0,0};
            #pragma unroll 8
            for (int d = 0; d < DINNER; d += 4) {
                float4 xv = *(const float4*)(xrow + d);
                float4 q0 = *(const float4*)(p0 + d);
                float4 q1 = *(const float4*)(p1 + d);
                v2f xl = {xv.x, xv.y}, xh = {xv.z, xv.w};
                v2f q0l = {q0.x, q0.y}, q0h = {q0.z, q0.w};
                v2f q1l = {q1.x, q1.y}, q1h = {q1.z, q1.w};
                a0 = __builtin_elementwise_fma(xl, q0l, a0);
                a0 = __builtin_elementwise_fma(xh, q0h, a0);
                a1 = __builtin_elementwise_fma(xl, q1l, a1);
                a1 = __builtin_elementwise_fma(xh, q1h, a1);
            }
            float r0 = a0.x + a0.y, r1 = a1.x + a1.y;
            if (j0 < 4) *(float2*)&dtraw[g][tt][j0] = make_float2(r0, r1);
            else        *(float2*)&Bsh[g][tt][j0-4] = make_float2(r0, r1);
        }
        __syncthreads();

        // scan chunk c (reads buf) — conv chunk c+1 (writes buf^1) follows in
        // the SAME phase: independent stream fills the scan's trans latency.
        const float* xs = &xcbuf[buf][g][0];
        if (__builtin_expect(sfast, 1)) {
            #pragma unroll
            for (int tt = 0; tt < CHK; ++tt) {
                float4 dr = *(const float4*)&dtraw[g][tt][0];    // broadcast
                float dv = fmaf(dr.x, dtw0, fmaf(dr.y, dtw1,
                           fmaf(dr.z, dtw2, fmaf(dr.w, dtw3, dtb_r))));
                float e  = __expf(dv);
                float p  = 1.f + e;
                float r  = fast_rcp(p);                  // exp(-delta)
                float dl = (dv > 80.f) ? dv : __logf(p); // delta
                dacc += dl;
                float ux = dl * xs[tt*XCP + ch];
                float4 B0 = *(const float4*)&Bsh[g][tt][0];
                float4 B1 = *(const float4*)&Bsh[g][tt][4];
                float4 B2 = *(const float4*)&Bsh[g][tt][8];
                float4 B3 = *(const float4*)&Bsh[g][tt][12];
                float r2 = r*r;
                v2f r2v = {r2, r2};
                v2f p01 = {r, r2};
                v2f p23 = p01*r2v, p45 = p23*r2v, p67 = p45*r2v, p89 = p67*r2v,
                    pAB = p89*r2v, pCD = pAB*r2v, pEF = pCD*r2v;
                v2f uxv = {ux, ux};
                h01 = __builtin_elementwise_fma(p01, h01, uxv*(v2f){B0.x,B0.y});
                h23 = __builtin_elementwise_fma(p23, h23, uxv*(v2f){B0.z,B0.w});
                h45 = __builtin_elementwise_fma(p45, h45, uxv*(v2f){B1.x,B1.y});
                h67 = __builtin_elementwise_fma(p67, h67, uxv*(v2f){B1.z,B1.w});
                h89 = __builtin_elementwise_fma(p89, h89, uxv*(v2f){B2.x,B2.y});
                hAB = __builtin_elementwise_fma(pAB, hAB, uxv*(v2f){B2.z,B2.w});
                hCD = __builtin_elementwise_fma(pCD, hCD, uxv*(v2f){B3.x,B3.y});
                hEF = __builtin_elementwise_fma(pEF, hEF, uxv*(v2f){B3.z,B3.w});
            }
        } else {
            const float* Arow = A_log + ch*DSTATE;
            for (int tt = 0; tt < CHK; ++tt) {
                float4 dr = *(const float4*)&dtraw[g][tt][0];
                float dv = fmaf(dr.x, dtw0, fmaf(dr.y, dtw1,
                           fmaf(dr.z, dtw2, fmaf(dr.w, dtw3, dtb_r))));
                float e  = __expf(dv);
                float dl = (dv > 15.f) ? dv : __logf(1.f + e);
                dacc += dl;
                float ux = dl * xs[tt*XCP + ch];
                const float* Brow = &Bsh[g][tt][0];
                float hv[16] = {h01.x,h01.y,h23.x,h23.y,h45.x,h45.y,h67.x,h67.y,
                                h89.x,h89.y,hAB.x,hAB.y,hCD.x,hCD.y,hEF.x,hEF.y};
                for (int i = 0; i < 16; ++i)
                    hv[i] = fmaf(__expf(-__expf(Arow[i])*dl), hv[i], ux*Brow[i]);
                h01=(v2f){hv[0],hv[1]};   h23=(v2f){hv[2],hv[3]};
                h45=(v2f){hv[4],hv[5]};   h67=(v2f){hv[6],hv[7]};
                h89=(v2f){hv[8],hv[9]};   hAB=(v2f){hv[10],hv[11]};
                hCD=(v2f){hv[12],hv[13]}; hEF=(v2f){hv[14],hv[15]};
            }
        }

        if (c + 1 < NCH) {   // conv chunk c+1 into the other buffer (t0 >= 12)
            float* xw = &xcbuf[buf^1][g][0];
            const float* xr = &xrl[g*GSEG + (c+1)*CHK];
            float e0 = fmaf(xr[0], w1, w0);
            float e1 = fmaf(xr[1], w1, w0);
            float e2 = fmaf(xr[2], w1, w0);
            float v = 0.f;
            #pragma unroll
            for (int tt = 0; tt < CHK; ++tt) {
                float e3 = fmaf(xr[tt+3], w1, w0);
                float acc = cb + e0*cw.x + e1*cw.y + e2*cw.z + e3*cw.w;
                v = silu_f(acc);
                xw[tt*XCP + ch] = v;
                e0 = e1; e1 = e2; e2 = e3;
            }
            if (g == NG-1 && c + 1 == NCH-1) xcl[ch] = v;    // t = 335
        }
        __syncthreads();   // scan reads + conv writes done before next A2
    }

    // ---- write partials to LDS (overlay dead xcbuf / Bsh regions) ----
    float* hpart = &xcbuf[0][0][0];      // needs 512*HSTR = 10240 <= 12672
    float* dsum  = &Bsh[0][0][0];        // needs 512 <= 768
    {
        float4* hp = (float4*)&hpart[(g*128 + ch)*HSTR];
        hp[0] = make_float4(h01.x,h01.y,h23.x,h23.y);
        hp[1] = make_float4(h45.x,h45.y,h67.x,h67.y);
        hp[2] = make_float4(h89.x,h89.y,hAB.x,hAB.y);
        hp[3] = make_float4(hCD.x,hCD.y,hEF.x,hEF.y);
        dsum[g*128 + ch] = dacc;
    }
    __syncthreads();

    // ---- E1 (parallel): combine | z-gate | C | mlp1 ----
    float H[16];
    if (tid < 128) {
        {
            const float4* hp = (const float4*)&hpart[tid*HSTR];
            float4 a = hp[0], bq = hp[1], cq = hp[2], dq = hp[3];
            H[0]=a.x;  H[1]=a.y;  H[2]=a.z;  H[3]=a.w;
            H[4]=bq.x; H[5]=bq.y; H[6]=bq.z; H[7]=bq.w;
            H[8]=cq.x; H[9]=cq.y; H[10]=cq.z;H[11]=cq.w;
            H[12]=dq.x;H[13]=dq.y;H[14]=dq.z;H[15]=dq.w;
        }
        for (int gg = 1; gg < NG; ++gg) {
            float D = dsum[gg*128 + tid];
            const float4* hp = (const float4*)&hpart[(gg*128 + tid)*HSTR];
            float4 a = hp[0], bq = hp[1], cq = hp[2], dq = hp[3];
            float hg[16] = {a.x,a.y,a.z,a.w,bq.x,bq.y,bq.z,bq.w,
                            cq.x,cq.y,cq.z,cq.w,dq.x,dq.y,dq.z,dq.w};
            if (structured) {
                float r = __expf(-D);
                float pw = 1.f;
                #pragma unroll
                for (int i = 0; i < 16; ++i) {
                    pw *= r;                      // r^(i+1)
                    H[i] = fmaf(pw, H[i], hg[i]);
                }
            } else {
                #pragma unroll
                for (int i = 0; i < 16; ++i)
                    H[i] = fmaf(__expf(-__expf(A_log[tid*DSTATE+i])*D), H[i], hg[i]);
            }
        }
    } else if (tid < 256) {
        const int c2 = tid - 128;                 // z-gate channel
        float a1 = 0.f, a0 = 0.f;
        for (int dm = 0; dm < DMODEL; ++dm) {
            float w = in_W[dm*(2*DINNER) + DINNER + c2];
            a1 = fmaf(embed_W[dm], w, a1);
            a0 = fmaf(embed_b[dm], w, a0);
        }
        float zv = fmaf(xrl[338], a1, a0);        // x_raw[335]
        zsil[c2] = silu_f(zv);
    } else if (tid < 320) {
        const int lane = tid - 256;               // C at t=335 (one wave)
        const int n = lane & 15, q = lane >> 4;
        float acc = 0.f;
        for (int d = q*32; d < q*32 + 32; ++d)
            acc = fmaf(xcl[d], xproj_W[d*36 + 20 + n], acc);
        acc += __shfl_xor(acc, 16);
        acc += __shfl_xor(acc, 32);
        if (lane < 16) Cl[n] = acc;
    } else if (tid >= 384) {
        const int lane = tid - 384;               // mlp1 (2 waves)
        const int j = lane >> 1, k = lane & 1;
        const float* xf = x_features + b*NFEAT;
        float acc = 0.f;
        const int f0 = k*82, f1 = (k ? NFEAT : 82);
        for (int f = f0; f < f1; ++f)
            acc = fmaf(xf[f], mlp_W1[f*MLPH + j], acc);
        acc += __shfl_xor(acc, 1);
        if (k == 0) mlph[j] = fmaxf(acc + mlp_b1[j], 0.f);
    }
    __syncthreads();

    // ---- E2: y (tid<128) | mlp2 (tid 128..191) ----
    if (tid < 128) {
        float acc = 0.f;
        #pragma unroll
        for (int i = 0; i < 16; ++i) acc = fmaf(H[i], Cl[i], acc);
        float y = acc + xcl[tid]*Dvec[tid];
        yv[tid] = y * zsil[tid];
    } else if (tid < 192) {
        const int lane = tid - 128;
        const int j = lane >> 1, k = lane & 1;
        float acc = 0.f;
        for (int kk = k*32; kk < k*32 + 32; ++kk)
            acc = fmaf(mlph[kk], mlp_W2[kk*32 + j], acc);
        acc += __shfl_xor(acc, 1);
        if (k == 0) hfin[64 + j] = acc + mlp_b2[j];
    }
    __syncthreads();

    // ---- E3: out projection (tid<256) ----
    if (tid < 256) {
        const int o = tid >> 2, k = tid & 3;
        float acc = 0.f;
        for (int d = k*32; d < k*32 + 32; ++d)
            acc = fmaf(yv[d], out_W[d*DMODEL + o], acc);
        acc += __shfl_xor(acc, 1);
        acc += __shfl_xor(acc, 2);
        if (k == 0) hfin[o] = acc;
    }
    __syncthreads();

    // ---- E4: head ----
    if (tid < 192) {
        const int o = tid >> 1, k = tid & 1;
        float acc = 0.f;
        for (int i = k*48; i < k*48 + 48; ++i)
            acc = fmaf(hfin[i], head_W[i*HORIZON + o], acc);
        acc += __shfl_xor(acc, 1);
        if (k == 0) out[b*HORIZON + o] = acc + head_b[o];
    }
}

extern "C" void kernel_launch(void* const* d_in, const int* in_sizes, int n_in,
                              void* d_out, int out_size, void* d_ws, size_t ws_size,
                              hipStream_t stream) {
    (void)in_sizes; (void)n_in; (void)out_size; (void)d_ws; (void)ws_size;
    mamba_one<<<BATCH, 512, 0, stream>>>(
        (const float*)d_in[0],  (const float*)d_in[1],  (const float*)d_in[2],
        (const float*)d_in[3],  (const float*)d_in[4],  (const float*)d_in[5],
        (const float*)d_in[6],  (const float*)d_in[7],  (const float*)d_in[8],
        (const float*)d_in[9],  (const float*)d_in[10], (const float*)d_in[11],
        (const float*)d_in[12], (const float*)d_in[13], (const float*)d_in[14],
        (const float*)d_in[15], (const float*)d_in[16], (const float*)d_in[17],
        (const float*)d_in[18], (float*)d_out);
}